// Round 10
// baseline (263.233 us; speedup 1.0000x reference)
//
#include <hip/hip_runtime.h>

#define DSX 60
#define SZ  64
#define NPT (DSX*SZ*SZ)        // 245760 points
#define NS_P 64
#define NS_Q 68
#define NS_R 68
#define NS_SZ (NS_P*NS_Q*NS_R) // 295936
#define P_PER_ROW 61440        // 245760/4 (float4 groups per W1 row)
#define KSPLIT 8
#define P_CHUNK (P_PER_ROW / KSPLIT)   // 7680
#define PB_SLAB (15*NS_Q*NS_R)         // 69360 (row-batch stride in PB)
#define NS_BLOCKS 1156                 // ceil(NS_SZ/256)
#define TR_BLOCKS (NPT / 64)           // 3840
#define PT_BLOCKS (NPT / 256)          // 960 conv blocks
#define PF_BLOCKS 512                  // prefetch blocks per conv launch
#define PF_ITERS  16                   // 512*256*16 fx4 = 32 MB per launch

typedef float fx4 __attribute__((ext_vector_type(4)));

__device__ __forceinline__ unsigned rne_bf16(float x) {
    unsigned b = __float_as_uint(x);
    return (b + 0x7fffu + ((b >> 16) & 1u)) >> 16;   // round-to-nearest-even bf16
}

// ---------------- fused prologue:
// blocks [0, NS_BLOCKS): PB0 = channel-sum(vinput) in ns layout; PB1 = 0
// blocks [NS_BLOCKS, NS_BLOCKS+TR_BLOCKS): syn transpose+pack to bf16 g-major
__global__ __launch_bounds__(256) void prologue(const float* __restrict__ vin,
                                                const float* __restrict__ syn,
                                                float* __restrict__ PB0,
                                                float* __restrict__ PB1,
                                                uint2* __restrict__ synP) {
    if (blockIdx.x < NS_BLOCKS) {
        int t = blockIdx.x * 256 + threadIdx.x;
        if (t >= NS_SZ) return;
        int r = t % NS_R;
        int q = (t / NS_R) % NS_Q;
        int p = t / (NS_R * NS_Q);
        float val = 0.f;
        if (p >= 2 && p < 62 && q >= 2 && q < 66 && r >= 2 && r < 66) {
            const float* b = vin + ((((size_t)(p - 2) * SZ) + (q - 2)) * SZ + (r - 2)) * 4;
            val = (b[0] + b[1]) + (b[2] + b[3]);
        }
        PB0[t] = val;
        PB1[t] = 0.f;
    } else {
        __shared__ float tile[64 * 65];
        int t0 = (blockIdx.x - NS_BLOCKS) * 64;
        const fx4* s4 = (const fx4*)syn;
#pragma unroll
        for (int r = 0; r < 4; r++) {
            int idx = r * 256 + threadIdx.x;      // 0..1023
            int pl = idx >> 4, g = idx & 15;
            fx4 v = s4[(size_t)(t0 + pl) * 16 + g];
            int base = pl * 65 + g * 4;
            tile[base] = v.x; tile[base + 1] = v.y; tile[base + 2] = v.z; tile[base + 3] = v.w;
        }
        __syncthreads();
        int l = threadIdx.x & 63;
        int wv = threadIdx.x >> 6; // 0..3
#pragma unroll
        for (int r = 0; r < 4; r++) {
            int g = r * 4 + wv;
            int base = l * 65 + g * 4;
            uint2 u;
            u.x = rne_bf16(tile[base])     | (rne_bf16(tile[base + 1]) << 16);
            u.y = rne_bf16(tile[base + 2]) | (rne_bf16(tile[base + 3]) << 16);
            synP[(size_t)g * NPT + t0 + l] = u;
        }
    }
}

// ---------------- conv (+ W1 prefetch side-blocks):
// blocks [0, PT_BLOCKS): core = <bf16 weights, PBin neighborhood>; PBout = 4*0.9*relu
// blocks [PT_BLOCKS, PT_BLOCKS+PF_BLOCKS): stream 32 MB slice of W1 into L2/L3
__global__ __launch_bounds__(256) void conv_kernel(const float* __restrict__ PBin,
                                                   const uint2* __restrict__ synP,
                                                   float* __restrict__ PBout,
                                                   const float* __restrict__ W1,
                                                   float* __restrict__ pfdump,
                                                   int slice) {
    if (blockIdx.x < PT_BLOCKS) {
        int t = blockIdx.x * 256 + threadIdx.x;
        int k = t & 63;
        int j = (t >> 6) & 63;
        int i = t >> 12;
        float acc = 0.f;
#pragma unroll
        for (int g = 0; g < 16; g++) {
            uint2 u = synP[(size_t)g * NPT + t];  // 512 B contiguous per wave-load
            float w0 = __uint_as_float(u.x << 16);
            float w1 = __uint_as_float(u.x & 0xffff0000u);
            float w2 = __uint_as_float(u.y << 16);
            float w3 = __uint_as_float(u.y & 0xffff0000u);
            int a = g >> 2, b = g & 3;
            const float* nrow = PBin + ((size_t)(i + a) * NS_Q + (j + b)) * NS_R + k;
            acc += w0 * nrow[0] + w1 * nrow[1] + w2 * nrow[2] + w3 * nrow[3];
        }
        PBout[((size_t)i * NS_Q + j) * NS_R + k] = acc > 0.f ? acc * 3.6f : 0.f;
    } else {
        // prefetch: read 32 MB of W1 (slice s) through L2/L3
        int b = blockIdx.x - PT_BLOCKS;       // 0..511
        const fx4* w = (const fx4*)W1 +
            (size_t)slice * (PF_BLOCKS * 256 * PF_ITERS) +
            (size_t)b * (256 * PF_ITERS) + threadIdx.x;
        float acc = 0.f;
#pragma unroll
        for (int it = 0; it < PF_ITERS; it++) {
            fx4 v = w[it * 256];
            acc += (v.x + v.y) + (v.z + v.w);
        }
        // data-dependent guard: keeps loads alive, store essentially never fires,
        // and is deterministic (same W1 -> same behavior every call)
        if (acc == 1234.56789f) pfdump[b] = acc;
    }
}

// ---------------- layer 1 split-K partials (PB holds 4*v5; 0.25 folded into fc2)
// ILP x2: two independent W1 float4 streams per thread
__global__ __launch_bounds__(256) void gemv1(const float* __restrict__ W1,
                                             const float* __restrict__ PB,
                                             float* __restrict__ partial) {
    int n = blockIdx.x >> 3;        // 0..1023
    int c = blockIdx.x & 7;         // chunk 0..7
    const fx4* w4 = (const fx4*)(W1 + (size_t)n * (P_PER_ROW * 4));
    float a0 = 0.f, a1 = 0.f, a2 = 0.f, a3 = 0.f;
#pragma unroll 5
    for (int it = 0; it < 15; it++) {
        int p1 = c * P_CHUNK + it * 256 + threadIdx.x;
        int p2 = p1 + 15 * 256;
        fx4 wa = w4[p1];
        fx4 wb = w4[p2];
        float sa = (wa.x + wa.y) + (wa.z + wa.w);
        float sb = (wb.x + wb.y) + (wb.z + wb.w);
        int i1 = p1 >> 12, j1 = (p1 >> 6) & 63, k1 = p1 & 63;
        int i2 = p2 >> 12, j2 = (p2 >> 6) & 63, k2 = p2 & 63;
        int base1 = ((i1 + 2) * NS_Q + (j1 + 2)) * NS_R + (k1 + 2);
        int base2 = ((i2 + 2) * NS_Q + (j2 + 2)) * NS_R + (k2 + 2);
        a0 += sa * PB[base1] + sb * PB[base2];
        a1 += sa * PB[base1 + PB_SLAB] + sb * PB[base2 + PB_SLAB];
        a2 += sa * PB[base1 + 2 * PB_SLAB] + sb * PB[base2 + 2 * PB_SLAB];
        a3 += sa * PB[base1 + 3 * PB_SLAB] + sb * PB[base2 + 3 * PB_SLAB];
    }
#pragma unroll
    for (int off = 32; off; off >>= 1) {
        a0 += __shfl_down(a0, off);
        a1 += __shfl_down(a1, off);
        a2 += __shfl_down(a2, off);
        a3 += __shfl_down(a3, off);
    }
    __shared__ float red[4][4];
    int lane = threadIdx.x & 63, wv = threadIdx.x >> 6;
    if (lane == 0) { red[wv][0] = a0; red[wv][1] = a1; red[wv][2] = a2; red[wv][3] = a3; }
    __syncthreads();
    if (threadIdx.x < 4) {
        int r = threadIdx.x;
        float s = (red[0][r] + red[1][r]) + (red[2][r] + red[3][r]);
        partial[((size_t)c * 4 + r) * 1024 + n] = s;
    }
}

// ---------------- layer 2: recombine split-K partials, relu(h1), then gemv vs W2
__global__ __launch_bounds__(256) void fc2(const float* __restrict__ W2,
                                           const float* __restrict__ b1,
                                           const float* __restrict__ b2,
                                           const float* __restrict__ partial,
                                           float* __restrict__ h2) {
    int n = blockIdx.x; // 0..127
    float a0 = 0.f, a1 = 0.f, a2 = 0.f, a3 = 0.f;
    for (int e = threadIdx.x; e < 1024; e += 256) {
        float w = W2[(size_t)n * 1024 + e];
        float be = b1[e];
#pragma unroll
        for (int r = 0; r < 4; r++) {
            float acc = 0.f;
#pragma unroll
            for (int cc = 0; cc < KSPLIT; cc++) acc += partial[(cc * 4 + r) * 1024 + e];
            float h = 0.25f * acc + be;
            h = h > 0.f ? h : 0.f;
            if (r == 0) a0 += w * h;
            else if (r == 1) a1 += w * h;
            else if (r == 2) a2 += w * h;
            else a3 += w * h;
        }
    }
#pragma unroll
    for (int off = 32; off; off >>= 1) {
        a0 += __shfl_down(a0, off);
        a1 += __shfl_down(a1, off);
        a2 += __shfl_down(a2, off);
        a3 += __shfl_down(a3, off);
    }
    __shared__ float red[4][4];
    int lane = threadIdx.x & 63, wv = threadIdx.x >> 6;
    if (lane == 0) { red[wv][0] = a0; red[wv][1] = a1; red[wv][2] = a2; red[wv][3] = a3; }
    __syncthreads();
    if (threadIdx.x < 4) {
        int r = threadIdx.x;
        float s = (red[0][r] + red[1][r]) + (red[2][r] + red[3][r]) + b2[n];
        h2[(size_t)r * 128 + n] = s > 0.f ? s : 0.f;
    }
}

// ---------------- layer 3: out[r*10+n] = sum_e W3[n,e]*h2[r,e] + b3[n]
__global__ __launch_bounds__(64) void fc3(const float* __restrict__ W3,
                                          const float* __restrict__ b3,
                                          const float* __restrict__ h2,
                                          float* __restrict__ out) {
    int t = threadIdx.x;
    if (t < 40) {
        int r = t / 10, n = t % 10;
        float a = b3[n];
        for (int e = 0; e < 128; e++) a += W3[(size_t)n * 128 + e] * h2[(size_t)r * 128 + e];
        out[t] = a;
    }
}

extern "C" void kernel_launch(void* const* d_in, const int* in_sizes, int n_in,
                              void* d_out, int out_size, void* d_ws, size_t ws_size,
                              hipStream_t stream) {
    const float* vin = (const float*)d_in[0];
    const float* syn = (const float*)d_in[1];
    const float* W1  = (const float*)d_in[2];
    const float* b1  = (const float*)d_in[3];
    const float* W2  = (const float*)d_in[4];
    const float* b2  = (const float*)d_in[5];
    const float* W3  = (const float*)d_in[6];
    const float* b3  = (const float*)d_in[7];
    float* out = (float*)d_out;

    float* ws = (float*)d_ws;
    float* PB0 = ws;                     // 295936
    float* PB1 = PB0 + NS_SZ;            // 295936
    float* partial = PB1 + NS_SZ;        // 32*1024
    float* h2 = partial + 32 * 1024;     // 512 (padded to 1024)
    float* pfdump = h2 + 1024;           // 512 floats (padded to 1024)
    uint2* synP = (uint2*)(pfdump + 1024); // NPT*16 uint2 = 31.5 MB, 8B-aligned

    prologue<<<NS_BLOCKS + TR_BLOCKS, 256, 0, stream>>>(vin, syn, PB0, PB1, synP);
    float* cur = PB0; float* nxt = PB1;
    for (int it = 0; it < 5; it++) {
        conv_kernel<<<PT_BLOCKS + PF_BLOCKS, 256, 0, stream>>>(cur, synP, nxt, W1, pfdump, it);
        float* tmp = cur; cur = nxt; nxt = tmp;
    }
    // cur holds 4*v5 in padded layout
    gemv1<<<1024 * KSPLIT, 256, 0, stream>>>(W1, cur, partial);
    fc2<<<128, 256, 0, stream>>>(W2, b1, b2, partial, h2);
    fc3<<<1, 64, 0, stream>>>(W3, b3, h2, out);
}